// Round 1
// baseline (517.164 us; speedup 1.0000x reference)
//
#include <hip/hip_runtime.h>
#include <math.h>

// ---------------------------------------------------------------------------
// MILossGaussian: soft (Gaussian-window) joint histogram -> mutual information
// x, y: float32 (2, 1, 96, 96, 96). Output: single float32 scalar.
//
// Key insight: sigma = (1/64)/2.3548 = 0.006635, bin spacing = 1/63 = 0.01587
// => window weight at |k| bins: k=1: 5.7e-2, k=2: 1.1e-5, k=3: 6.5e-12.
// Truncate window at +/-3 bins: joint-hist relative error ~1e-11, vastly below
// the 2e-2 output threshold. So the big einsum collapses to a sparse 7x7
// outer-product scatter per element.
// ---------------------------------------------------------------------------

#define NBINS 64
#define RAD 3
#define WWIN 7

static constexpr double kSigmaD  = 0.015625 / 2.3548200450309493;   // BIN_WIDTH/(2*sqrt(2*ln2))
static constexpr double kInv2S2D = 1.0 / (2.0 * kSigmaD * kSigmaD);
static constexpr double kCoefD   = kSigmaD / 2.5066282746310002;    // sigma / sqrt(2*pi)
static constexpr float  kInv2S2  = (float)kInv2S2D;
static constexpr float  kCoef    = (float)kCoefD;
static constexpr float  kInvStep = 63.0f;          // bins are b/63 (linspace 0..1, 64 pts)
static constexpr float  kStep    = 1.0f / 63.0f;
static constexpr float  kEps     = 1e-10f;

__global__ void zero_ws_kernel(float* __restrict__ p, int n) {
    int i = blockIdx.x * blockDim.x + threadIdx.x;
    if (i < n) p[i] = 0.0f;
}

__global__ __launch_bounds__(256) void hist_kernel(
        const float* __restrict__ x, const float* __restrict__ y,
        float* __restrict__ hist, int P) {
    __shared__ float lh[NBINS * NBINS];   // 16 KB private joint histogram
    for (int i = threadIdx.x; i < NBINS * NBINS; i += blockDim.x) lh[i] = 0.0f;
    __syncthreads();

    const int n = blockIdx.y;
    const float* __restrict__ xp = x + (size_t)n * P;
    const float* __restrict__ yp = y + (size_t)n * P;

    const int stride = gridDim.x * blockDim.x;
    for (int p = blockIdx.x * blockDim.x + threadIdx.x; p < P; p += stride) {
        const float vx = xp[p];
        const float vy = yp[p];
        const int cx = (int)(vx * kInvStep + 0.5f);   // nearest bin
        const int cy = (int)(vy * kInvStep + 0.5f);

        float wx[WWIN], wy[WWIN];
#pragma unroll
        for (int k = 0; k < WWIN; k++) {
            const int bx = cx + k - RAD;
            const float dx = vx - (float)bx * kStep;
            const float ex = __expf(-(dx * dx) * kInv2S2) * kCoef;
            wx[k] = (bx >= 0 && bx < NBINS) ? ex : 0.0f;

            const int by = cy + k - RAD;
            const float dy = vy - (float)by * kStep;
            const float ey = __expf(-(dy * dy) * kInv2S2) * kCoef;
            wy[k] = (by >= 0 && by < NBINS) ? ey : 0.0f;
        }

#pragma unroll
        for (int i = 0; i < WWIN; i++) {
            const float wxi = wx[i];
            if (wxi == 0.0f) continue;                 // OOB row: skip 7 atomics
            int bi = cx + i - RAD;                     // in range when wxi != 0
            float* rowp = &lh[bi * NBINS];
#pragma unroll
            for (int j = 0; j < WWIN; j++) {
                int bj = cy + j - RAD;
                bj = bj < 0 ? 0 : (bj > NBINS - 1 ? NBINS - 1 : bj);  // weight is 0 if OOB
                atomicAdd(&rowp[bj], wxi * wy[j]);
            }
        }
    }

    __syncthreads();
    float* __restrict__ gh = hist + (size_t)n * NBINS * NBINS;
    for (int i = threadIdx.x; i < NBINS * NBINS; i += blockDim.x) {
        const float v = lh[i];
        if (v != 0.0f) atomicAdd(&gh[i], v);
    }
}

__device__ __forceinline__ float block_sum_bcast(float v, float* sm) {
    // 256 threads = 4 waves of 64
#pragma unroll
    for (int off = 32; off > 0; off >>= 1) v += __shfl_down(v, off, 64);
    __syncthreads();                       // protect sm reuse across calls
    const int lane = threadIdx.x & 63;
    const int wid  = threadIdx.x >> 6;
    if (lane == 0) sm[wid] = v;
    __syncthreads();
    return sm[0] + sm[1] + sm[2] + sm[3];
}

__global__ __launch_bounds__(256) void finalize_kernel(
        const float* __restrict__ hist, float* __restrict__ out) {
    __shared__ float sm[4];
    __shared__ float sx[NBINS];
    __shared__ float sy[NBINS];

    float res[2];
#pragma unroll
    for (int n = 0; n < 2; n++) {
        const float* __restrict__ h = hist + n * NBINS * NBINS;

        // hist_norm = sum(h) + eps
        float s = 0.0f;
        for (int i = threadIdx.x; i < NBINS * NBINS; i += 256) s += h[i];
        const float S = block_sum_bcast(s, sm) + kEps;
        const float invS = 1.0f / S;

        // joint entropy partial: sum p*log(p+eps)
        float ej = 0.0f;
        for (int i = threadIdx.x; i < NBINS * NBINS; i += 256) {
            const float p = h[i] * invS;
            ej += p * __logf(p + kEps);
        }

        // marginals: rows -> p_x (sum over c), cols -> p_y (sum over b)
        if (threadIdx.x < NBINS) {
            float px = 0.0f;
            const float* rp = &h[threadIdx.x * NBINS];
            for (int c = 0; c < NBINS; c++) px += rp[c];
            px *= invS;
            sx[threadIdx.x] = px * __logf(px + kEps);
        } else if (threadIdx.x < 2 * NBINS) {
            const int c = threadIdx.x - NBINS;
            float py = 0.0f;
            for (int b = 0; b < NBINS; b++) py += h[b * NBINS + c];
            py *= invS;
            sy[c] = py * __logf(py + kEps);
        }

        const float EJ = block_sum_bcast(ej, sm);   // syncthreads inside orders sx/sy
        const float mx = (threadIdx.x < NBINS) ? sx[threadIdx.x] : 0.0f;
        const float my = (threadIdx.x < NBINS) ? sy[threadIdx.x] : 0.0f;
        const float EX = block_sum_bcast(mx, sm);
        const float EY = block_sum_bcast(my, sm);

        // ent_* = -sum(...); ratio (ent_x+ent_y)/ent_joint
        res[n] = (EX + EY) / EJ;                    // signs cancel
        __syncthreads();
    }

    if (threadIdx.x == 0) out[0] = -0.5f * (res[0] + res[1]);
}

extern "C" void kernel_launch(void* const* d_in, const int* in_sizes, int n_in,
                              void* d_out, int out_size, void* d_ws, size_t ws_size,
                              hipStream_t stream) {
    const float* x = (const float*)d_in[0];
    const float* y = (const float*)d_in[1];
    float* hist = (float*)d_ws;                 // 2 * 64 * 64 floats = 32 KB
    float* out  = (float*)d_out;

    const int N = 2;
    const int P = in_sizes[0] / N;              // 96*96*96 = 884736

    const int histElems = N * NBINS * NBINS;
    zero_ws_kernel<<<(histElems + 255) / 256, 256, 0, stream>>>(hist, histElems);

    dim3 grid(256, N);                          // 512 blocks, 2 per CU
    hist_kernel<<<grid, 256, 0, stream>>>(x, y, hist, P);

    finalize_kernel<<<1, 256, 0, stream>>>(hist, out);
}

// Round 2
// 297.913 us; speedup vs baseline: 1.7360x; 1.7360x over previous
//
#include <hip/hip_runtime.h>
#include <math.h>

// ---------------------------------------------------------------------------
// MILossGaussian: soft (Gaussian-window) joint histogram -> mutual information
// x, y: float32 (2, 1, 96, 96, 96). Output: single float32 scalar.
//
// sigma = (1/64)/2.3548 = 0.006635, bin spacing = 1/63 = 0.01587.
// Weight at distance d steps: exp(-2.862 d^2). Truncating at +/-2 bins around
// the NEAREST bin drops only terms with d >= 2.5 steps -> <= 1.7e-8 relative.
// So the (N,64,P)x(N,64,P) einsum collapses to a 5x5 outer-product scatter.
//
// R1: RAD 3->2 (49->25 atomics/elem) + 4x occupancy (2048 blocks, 8/CU) to
// discriminate LDS-atomic-throughput-bound vs latency-bound.
// ---------------------------------------------------------------------------

#define NBINS 64
#define RAD 2
#define WWIN 5

static constexpr double kSigmaD  = 0.015625 / 2.3548200450309493;   // BIN_WIDTH/(2*sqrt(2*ln2))
static constexpr double kInv2S2D = 1.0 / (2.0 * kSigmaD * kSigmaD);
static constexpr double kCoefD   = kSigmaD / 2.5066282746310002;    // sigma / sqrt(2*pi)
static constexpr float  kInv2S2  = (float)kInv2S2D;
static constexpr float  kCoef    = (float)kCoefD;
static constexpr float  kInvStep = 63.0f;          // bins are b/63 (linspace 0..1, 64 pts)
static constexpr float  kStep    = 1.0f / 63.0f;
static constexpr float  kEps     = 1e-10f;

// zero the 2*64*64 global hist AND the output scalar (harness poisons both)
__global__ void zero_ws_kernel(float* __restrict__ hist, float* __restrict__ out, int n) {
    int i = blockIdx.x * blockDim.x + threadIdx.x;
    if (i < n) hist[i] = 0.0f;
    if (i == 0) out[0] = 0.0f;
}

__global__ __launch_bounds__(256) void hist_kernel(
        const float* __restrict__ x, const float* __restrict__ y,
        float* __restrict__ hist, int P) {
    __shared__ float lh[NBINS * NBINS];   // 16 KB private joint histogram
    for (int i = threadIdx.x; i < NBINS * NBINS; i += blockDim.x) lh[i] = 0.0f;
    __syncthreads();

    const int n = blockIdx.y;
    const float* __restrict__ xp = x + (size_t)n * P;
    const float* __restrict__ yp = y + (size_t)n * P;

    const int stride = gridDim.x * blockDim.x;
    for (int p = blockIdx.x * blockDim.x + threadIdx.x; p < P; p += stride) {
        const float vx = xp[p];
        const float vy = yp[p];
        const int cx = (int)(vx * kInvStep + 0.5f);   // nearest bin, in [0,63]
        const int cy = (int)(vy * kInvStep + 0.5f);

        float wx[WWIN], wy[WWIN];
#pragma unroll
        for (int k = 0; k < WWIN; k++) {
            const int bx = cx + k - RAD;
            const float dx = vx - (float)bx * kStep;
            const float ex = __expf(-(dx * dx) * kInv2S2) * kCoef;
            wx[k] = (bx >= 0 && bx < NBINS) ? ex : 0.0f;

            const int by = cy + k - RAD;
            const float dy = vy - (float)by * kStep;
            const float ey = __expf(-(dy * dy) * kInv2S2) * kCoef;
            wy[k] = (by >= 0 && by < NBINS) ? ey : 0.0f;
        }

#pragma unroll
        for (int i = 0; i < WWIN; i++) {
            const float wxi = wx[i];
            if (wxi == 0.0f) continue;                 // OOB row: skip 5 atomics
            const int bi = cx + i - RAD;               // in range when wxi != 0
            float* rowp = &lh[bi * NBINS];
#pragma unroll
            for (int j = 0; j < WWIN; j++) {
                int bj = cy + j - RAD;
                bj = bj < 0 ? 0 : (bj > NBINS - 1 ? NBINS - 1 : bj);  // weight 0 if OOB
                atomicAdd(&rowp[bj], wxi * wy[j]);
            }
        }
    }

    __syncthreads();
    float* __restrict__ gh = hist + (size_t)n * NBINS * NBINS;
    for (int i = threadIdx.x; i < NBINS * NBINS; i += blockDim.x) {
        atomicAdd(&gh[i], lh[i]);
    }
}

__device__ __forceinline__ float block_sum_bcast(float v, float* sm) {
    // 256 threads = 4 waves of 64
#pragma unroll
    for (int off = 32; off > 0; off >>= 1) v += __shfl_down(v, off, 64);
    __syncthreads();                       // protect sm reuse across calls
    const int lane = threadIdx.x & 63;
    const int wid  = threadIdx.x >> 6;
    if (lane == 0) sm[wid] = v;
    __syncthreads();
    return sm[0] + sm[1] + sm[2] + sm[3];
}

// grid = 2 blocks, one per n; each atomically adds -0.5*ratio into out[0].
// Two-float f32 atomic add is order-independent bitwise => deterministic.
__global__ __launch_bounds__(256) void finalize_kernel(
        const float* __restrict__ hist, float* __restrict__ out) {
    __shared__ float sm[4];
    __shared__ float sx[NBINS];
    __shared__ float sy[NBINS];

    const int n = blockIdx.x;
    const float* __restrict__ h = hist + (size_t)n * NBINS * NBINS;

    // hist_norm = sum(h) + eps
    float s = 0.0f;
    for (int i = threadIdx.x; i < NBINS * NBINS; i += 256) s += h[i];
    const float S = block_sum_bcast(s, sm) + kEps;
    const float invS = 1.0f / S;

    // joint entropy partial: sum p*log(p+eps)
    float ej = 0.0f;
    for (int i = threadIdx.x; i < NBINS * NBINS; i += 256) {
        const float p = h[i] * invS;
        ej += p * __logf(p + kEps);
    }

    // marginals: rows -> p_x (sum over c), cols -> p_y (sum over b)
    if (threadIdx.x < NBINS) {
        float px = 0.0f;
        const float* rp = &h[threadIdx.x * NBINS];
        for (int c = 0; c < NBINS; c++) px += rp[c];
        px *= invS;
        sx[threadIdx.x] = px * __logf(px + kEps);
    } else if (threadIdx.x < 2 * NBINS) {
        const int c = threadIdx.x - NBINS;
        float py = 0.0f;
        for (int b = 0; b < NBINS; b++) py += h[b * NBINS + c];
        py *= invS;
        sy[c] = py * __logf(py + kEps);
    }

    const float EJ = block_sum_bcast(ej, sm);   // syncthreads inside orders sx/sy
    const float mx = (threadIdx.x < NBINS) ? sx[threadIdx.x] : 0.0f;
    const float my = (threadIdx.x < NBINS) ? sy[threadIdx.x] : 0.0f;
    const float EX = block_sum_bcast(mx, sm);
    const float EY = block_sum_bcast(my, sm);

    // mean over n of (ent_x+ent_y)/ent_joint, negated; signs cancel in ratio
    if (threadIdx.x == 0) atomicAdd(out, -0.5f * ((EX + EY) / EJ));
}

extern "C" void kernel_launch(void* const* d_in, const int* in_sizes, int n_in,
                              void* d_out, int out_size, void* d_ws, size_t ws_size,
                              hipStream_t stream) {
    const float* x = (const float*)d_in[0];
    const float* y = (const float*)d_in[1];
    float* hist = (float*)d_ws;                 // 2 * 64 * 64 floats = 32 KB
    float* out  = (float*)d_out;

    const int N = 2;
    const int P = in_sizes[0] / N;              // 96*96*96 = 884736

    const int histElems = N * NBINS * NBINS;
    zero_ws_kernel<<<(histElems + 255) / 256, 256, 0, stream>>>(hist, out, histElems);

    dim3 grid(1024, N);                         // 2048 blocks -> 8/CU, 32 waves/CU
    hist_kernel<<<grid, 256, 0, stream>>>(x, y, hist, P);

    finalize_kernel<<<2, 256, 0, stream>>>(hist, out);
}

// Round 3
// 101.459 us; speedup vs baseline: 5.0973x; 2.9363x over previous
//
#include <hip/hip_runtime.h>
#include <math.h>

// ---------------------------------------------------------------------------
// MILossGaussian via MFMA: hist_joint(64x64) = Wx(64,P) . Wy^T(P,64) per n.
//
// sigma = (1/64)/2.3548 -> weight exp(-2.8613*d^2) in bin-step units d.
// 5-bin window (RAD=2) -> truncation error <= 1.7e-8 relative.
// R2: replace the LDS-atomic scatter (measured structural ~3.2 cyc/lane-atomic,
// occupancy-independent) with dense f16 LDS tiles consumed by
// v_mfma_f32_32x32x16_f16. Columns are thread-private -> plain ds_write_b16.
// kCoef (sigma/sqrt(2pi)) dropped: p_joint is scale-invariant (eps ~8e-12 shift).
// Window CENTER clamped to [2,61] with delta from true position: stamp always
// in-bounds, weights exact for the covered bins, uniform control flow.
// C vs C^T layout ambiguity is harmless: output symmetric under x<->y.
// ---------------------------------------------------------------------------

#define NBINS 64
#define BK 240                 // K-chunk per block iteration
#define LDA (BK + 8)           // f16 row stride; 248*2=496 bytes = 31*16 -> b128-aligned rows
#define NKB (BK / 16)          // 15 MFMA k-steps per chunk

typedef _Float16 half8   __attribute__((ext_vector_type(8)));
typedef float    floatx16 __attribute__((ext_vector_type(16)));

static constexpr double kSigmaD = 0.015625 / 2.3548200450309493;  // BIN_WIDTH/(2*sqrt(2*ln2))
static constexpr double kAcD    = (1.0 / (63.0 * 63.0)) / (2.0 * kSigmaD * kSigmaD);
static constexpr float  kAc     = (float)kAcD;                    // 2.86131
static constexpr float  kEps    = 1e-10f;

// zero the 2*64*64 global hist AND the output scalar (harness poisons both)
__global__ void zero_ws_kernel(float* __restrict__ hist, float* __restrict__ out, int n) {
    int i = blockIdx.x * blockDim.x + threadIdx.x;
    if (i < n) hist[i] = 0.0f;
    if (i == 0) out[0] = 0.0f;
}

__global__ __launch_bounds__(256) void hist_gemm_kernel(
        const float* __restrict__ x, const float* __restrict__ y,
        float* __restrict__ hist, int P, int elemsPerBlock) {
    __shared__ _Float16 Ax[NBINS * LDA];   // Wx tile: [bin_x][k]  (31 KB)
    __shared__ _Float16 By[NBINS * LDA];   // Wy tile: [bin_y][k]  (31 KB)

    const int t    = threadIdx.x;
    const int lane = t & 63;
    const int wave = t >> 6;
    const int qi   = wave >> 1;            // C row-half   (bin_x 32-block)
    const int qj   = wave & 1;             // C col-half   (bin_y 32-block)
    const int n    = blockIdx.y;

    // one-time tile zero (f32 stores; LDA*2 bytes divisible by 4)
    {
        float* a4 = (float*)Ax;
        float* b4 = (float*)By;
        const int ndw = NBINS * LDA / 2;
        for (int i = t; i < ndw; i += 256) { a4[i] = 0.0f; b4[i] = 0.0f; }
    }

    floatx16 acc = {};
    const float* __restrict__ xp = x + (size_t)n * P;
    const float* __restrict__ yp = y + (size_t)n * P;
    const int base    = blockIdx.x * elemsPerBlock;
    const int nElems  = elemsPerBlock;
    const int nChunks = (nElems + BK - 1) / BK;

    int pcx = 2, pcy = 2;                  // previous stamp centers (init: rows 0..4 are zero)
    __syncthreads();

    for (int c = 0; c < nChunks; ++c) {
        const int off = c * BK + t;        // tile column p = t
        float wx[5], wy[5];
        int cx = 2, cy = 2;
        const bool valid = (t < BK) && (off < nElems);
        if (valid) {
            const float vx = xp[base + off] * 63.0f;
            const float vy = yp[base + off] * 63.0f;
            cx = min(max((int)(vx + 0.5f), 2), 61);
            cy = min(max((int)(vy + 0.5f), 2), 61);
            const float dx = vx - (float)cx;
            const float dy = vy - (float)cy;
#pragma unroll
            for (int k = 0; k < 5; ++k) {
                const float ddx = dx - (float)(k - 2);
                const float ddy = dy - (float)(k - 2);
                wx[k] = __expf(-kAc * ddx * ddx);
                wy[k] = __expf(-kAc * ddy * ddy);
            }
        } else {
#pragma unroll
            for (int k = 0; k < 5; ++k) { wx[k] = 0.0f; wy[k] = 0.0f; }
        }

        if (t < BK) {
            // un-write previous stamp, then write new one (order matters if rows overlap)
#pragma unroll
            for (int k = 0; k < 5; ++k) {
                Ax[(pcx - 2 + k) * LDA + t] = (_Float16)0.0f;
                By[(pcy - 2 + k) * LDA + t] = (_Float16)0.0f;
            }
#pragma unroll
            for (int k = 0; k < 5; ++k) {
                Ax[(cx - 2 + k) * LDA + t] = (_Float16)wx[k];
                By[(cy - 2 + k) * LDA + t] = (_Float16)wy[k];
            }
        }
        pcx = cx; pcy = cy;
        __syncthreads();                   // tile ready

        // A[m=lane&31][k=8*(lane>>5)+j], B mirrored; both read k-contiguous rows
        const int rA = qi * 32 + (lane & 31);
        const int rB = qj * 32 + (lane & 31);
        const int kq = 8 * (lane >> 5);
#pragma unroll
        for (int kb = 0; kb < NKB; ++kb) {
            const half8 a = *(const half8*)&Ax[rA * LDA + kb * 16 + kq];
            const half8 b = *(const half8*)&By[rB * LDA + kb * 16 + kq];
            acc = __builtin_amdgcn_mfma_f32_32x32x16_f16(a, b, acc, 0, 0, 0);
        }
        __syncthreads();                   // tile consumed; safe to rewrite next iter
    }

    // epilogue: C/D layout (measured): col=lane&31, row=(r&3)+8*(r>>2)+4*(lane>>5)
    float* __restrict__ gh = hist + (size_t)n * NBINS * NBINS;
#pragma unroll
    for (int r = 0; r < 16; ++r) {
        const int row = qi * 32 + (r & 3) + 8 * (r >> 2) + 4 * (lane >> 5);
        const int col = qj * 32 + (lane & 31);
        atomicAdd(&gh[row * NBINS + col], acc[r]);
    }
}

__device__ __forceinline__ float block_sum_bcast(float v, float* sm) {
#pragma unroll
    for (int off = 32; off > 0; off >>= 1) v += __shfl_down(v, off, 64);
    __syncthreads();
    const int lane = threadIdx.x & 63;
    const int wid  = threadIdx.x >> 6;
    if (lane == 0) sm[wid] = v;
    __syncthreads();
    return sm[0] + sm[1] + sm[2] + sm[3];
}

// grid = 2 blocks (one per n); each atomically adds -0.5*ratio into out[0].
__global__ __launch_bounds__(256) void finalize_kernel(
        const float* __restrict__ hist, float* __restrict__ out) {
    __shared__ float sm[4];
    __shared__ float sx[NBINS];
    __shared__ float sy[NBINS];

    const int n = blockIdx.x;
    const float* __restrict__ h = hist + (size_t)n * NBINS * NBINS;

    float s = 0.0f;
    for (int i = threadIdx.x; i < NBINS * NBINS; i += 256) s += h[i];
    const float S = block_sum_bcast(s, sm) + kEps;
    const float invS = 1.0f / S;

    float ej = 0.0f;
    for (int i = threadIdx.x; i < NBINS * NBINS; i += 256) {
        const float p = h[i] * invS;
        ej += p * __logf(p + kEps);
    }

    if (threadIdx.x < NBINS) {
        float px = 0.0f;
        const float* rp = &h[threadIdx.x * NBINS];
        for (int c = 0; c < NBINS; c++) px += rp[c];
        px *= invS;
        sx[threadIdx.x] = px * __logf(px + kEps);
    } else if (threadIdx.x < 2 * NBINS) {
        const int c = threadIdx.x - NBINS;
        float py = 0.0f;
        for (int b = 0; b < NBINS; b++) py += h[b * NBINS + c];
        py *= invS;
        sy[c] = py * __logf(py + kEps);
    }

    const float EJ = block_sum_bcast(ej, sm);
    const float mx = (threadIdx.x < NBINS) ? sx[threadIdx.x] : 0.0f;
    const float my = (threadIdx.x < NBINS) ? sy[threadIdx.x] : 0.0f;
    const float EX = block_sum_bcast(mx, sm);
    const float EY = block_sum_bcast(my, sm);

    if (threadIdx.x == 0) atomicAdd(out, -0.5f * ((EX + EY) / EJ));
}

extern "C" void kernel_launch(void* const* d_in, const int* in_sizes, int n_in,
                              void* d_out, int out_size, void* d_ws, size_t ws_size,
                              hipStream_t stream) {
    const float* x = (const float*)d_in[0];
    const float* y = (const float*)d_in[1];
    float* hist = (float*)d_ws;            // 2 * 64 * 64 floats = 32 KB
    float* out  = (float*)d_out;

    const int N = 2;
    const int P = in_sizes[0] / N;         // 884736
    const int blocksPerN = 256;            // 512 blocks total -> 2/CU (LDS 62 KB/block)
    const int elemsPerBlock = P / blocksPerN;   // 3456 (exact)

    const int histElems = N * NBINS * NBINS;
    zero_ws_kernel<<<(histElems + 255) / 256, 256, 0, stream>>>(hist, out, histElems);

    dim3 grid(blocksPerN, N);
    hist_gemm_kernel<<<grid, 256, 0, stream>>>(x, y, hist, P, elemsPerBlock);

    finalize_kernel<<<2, 256, 0, stream>>>(hist, out);
}